// Round 1
// baseline (283.269 us; speedup 1.0000x reference)
//
#include <hip/hip_runtime.h>
#include <math.h>

#define BB    32
#define KMAX  2048
#define QDIM  512
#define VDIM  512
#define NMIX  8
#define EPSV  1e-6f
#define NEGINF -3.40282347e38f
#define TWO_PI 6.28318530717958647692f

// params layout per b (24 floats): [0..7]=myu, [8..15]=inv2v, [16..23]=coef (w/sqrt(2*pi*v+eps))
__global__ void gmm_proj_kernel(const float* __restrict__ query,
                                const float* __restrict__ Wg, const float* __restrict__ bg,
                                const float* __restrict__ Wb, const float* __restrict__ bb,
                                const float* __restrict__ Wk, const float* __restrict__ bk,
                                float* __restrict__ params)
{
    int b = blockIdx.x;
    int t = threadIdx.x;           // 256 threads = 4 waves
    int wave = t >> 6, lane = t & 63;
    __shared__ float dots[24];

    const float4* q4 = (const float4*)(query + (size_t)b * QDIM);
    for (int j = wave; j < 24; j += 4) {
        int set = j >> 3, m = j & 7;
        const float* Wrow = (set == 0 ? Wg : (set == 1 ? Wb : Wk)) + (size_t)m * QDIM;
        const float4* W4 = (const float4*)Wrow;
        float s = 0.f;
        for (int d = lane; d < QDIM / 4; d += 64) {
            float4 a = q4[d], w = W4[d];
            s += a.x * w.x + a.y * w.y + a.z * w.z + a.w * w.w;
        }
        #pragma unroll
        for (int off = 32; off; off >>= 1) s += __shfl_down(s, off, 64);
        if (lane == 0) dots[j] = s;
    }
    __syncthreads();

    if (t == 0) {
        float g[8], mx = -1e30f;
        #pragma unroll
        for (int m = 0; m < 8; m++) { g[m] = dots[m] + bg[m]; mx = fmaxf(mx, g[m]); }
        float sum = 0.f;
        #pragma unroll
        for (int m = 0; m < 8; m++) { g[m] = expf(g[m] - mx); sum += g[m]; }
        float inv_sum = 1.f / sum;
        float* p = params + b * 24;
        #pragma unroll
        for (int m = 0; m < 8; m++) {
            float w   = g[m] * inv_sum;
            float v   = expf(dots[8 + m]  + bb[m]);
            float myu = expf(dots[16 + m] + bk[m]);
            p[m]      = myu;
            p[8 + m]  = 1.f / (2.f * v + EPSV);
            p[16 + m] = w * rsqrtf(TWO_PI * v + EPSV);
        }
    }
}

// One block per (b, k-split). Computes aw for its k-chunk (writes to global aw
// output), then streams value[b, k-chunk, :] accumulating a partial cv row.
__global__ void gmm_aw_cv_partial_kernel(const float* __restrict__ value,
                                         const int*   __restrict__ mask,
                                         const float* __restrict__ params,
                                         float* __restrict__ aw_out,    // [B][KMAX]
                                         float* __restrict__ partial,   // [B][nsplit][VDIM]
                                         int nsplit, int kchunk)
{
    int b = blockIdx.x / nsplit;
    int s = blockIdx.x % nsplit;
    int t = threadIdx.x;            // 128 threads
    __shared__ float aw_s[256];     // max kchunk

    const float* p = params + b * 24;
    int k0 = s * kchunk;

    for (int k = t; k < kchunk; k += 128) {
        float j = (float)(k0 + k);
        float aw = 0.f;
        #pragma unroll
        for (int m = 0; m < 8; m++) {
            float d = j - p[m];
            aw += p[16 + m] * expf(-d * d * p[8 + m]);
        }
        if (mask[(size_t)b * KMAX + k0 + k] == 0) aw = NEGINF;
        aw_s[k] = aw;
        aw_out[(size_t)b * KMAX + k0 + k] = aw;
    }
    __syncthreads();

    const float4* vb = (const float4*)(value + ((size_t)b * KMAX + k0) * VDIM);
    float4 acc = make_float4(0.f, 0.f, 0.f, 0.f);
    #pragma unroll 4
    for (int kk = 0; kk < kchunk; kk++) {
        float a = aw_s[kk];
        float4 v = vb[(size_t)kk * (VDIM / 4) + t];
        acc.x += a * v.x; acc.y += a * v.y; acc.z += a * v.z; acc.w += a * v.w;
    }
    ((float4*)(partial + ((size_t)b * nsplit + s) * VDIM))[t] = acc;
}

__global__ void gmm_reduce_kernel(const float* __restrict__ partial,
                                  float* __restrict__ cv, int nsplit)
{
    int idx = blockIdx.x * blockDim.x + threadIdx.x;  // B*VDIM = 16384
    int b = idx >> 9;
    int d = idx & 511;
    const float* p = partial + (size_t)b * nsplit * VDIM + d;
    float sum = 0.f;
    for (int i = 0; i < nsplit; i++) sum += p[(size_t)i * VDIM];
    cv[idx] = sum;
}

extern "C" void kernel_launch(void* const* d_in, const int* in_sizes, int n_in,
                              void* d_out, int out_size, void* d_ws, size_t ws_size,
                              hipStream_t stream) {
    // inputs: 0 key_feat (UNUSED), 1 value, 2 query, 3 mask,
    //         4 W_gamma, 5 b_gamma, 6 W_beta, 7 b_beta, 8 W_kappa, 9 b_kappa
    const float* value = (const float*)d_in[1];
    const float* query = (const float*)d_in[2];
    const int*   mask  = (const int*)d_in[3];
    const float* Wg = (const float*)d_in[4];
    const float* bg = (const float*)d_in[5];
    const float* Wb = (const float*)d_in[6];
    const float* bb = (const float*)d_in[7];
    const float* Wk = (const float*)d_in[8];
    const float* bk = (const float*)d_in[9];

    float* out = (float*)d_out;
    float* cv  = out;                 // [B][VDIM]  = 16384 floats
    float* aw  = out + BB * VDIM;     // [B][KMAX]  = 65536 floats

    float* params  = (float*)d_ws;    // [B][24] = 768 floats (3072 B, 16B-aligned)
    float* partial = params + BB * 24;

    // pick largest k-split whose partial buffer fits in ws (4 MiB at nsplit=64)
    int nsplit = 64;
    while (nsplit > 8 &&
           (size_t)(BB * 24 + (size_t)BB * nsplit * VDIM) * sizeof(float) > ws_size)
        nsplit >>= 1;
    int kchunk = KMAX / nsplit;

    gmm_proj_kernel<<<BB, 256, 0, stream>>>(query, Wg, bg, Wb, bb, Wk, bk, params);
    gmm_aw_cv_partial_kernel<<<BB * nsplit, 128, 0, stream>>>(
        value, mask, params, aw, partial, nsplit, kchunk);
    gmm_reduce_kernel<<<(BB * VDIM) / 256, 256, 0, stream>>>(partial, cv, nsplit);
}

// Round 2
// 270.220 us; speedup vs baseline: 1.0483x; 1.0483x over previous
//
#include <hip/hip_runtime.h>
#include <math.h>

#define BB     32
#define KMAX   2048
#define QDIM   512
#define VDIM   512
#define NMIX   8
#define EPSV   1e-6f
#define NEGINF -3.40282347e38f
#define TWO_PI 6.28318530717958647692f
#define NSPLIT 64
#define KCHUNK (KMAX / NSPLIT)   // 32

// One fused kernel. Grid = BB*NSPLIT blocks x 128 threads.
// Each block: (1) redundantly computes the 24 q-projections for its batch b
// (48 KB of W read from L2 per block), (2) derives the 8 Gaussian-mixture
// params, (3) computes aw for its 32-k chunk and writes it, (4) streams its
// 32x512 fp32 value chunk with float4 loads, atomically accumulating into cv.
__global__ __launch_bounds__(128) void gmm_fused_kernel(
    const float* __restrict__ value,
    const float* __restrict__ query,
    const int*   __restrict__ mask,
    const float* __restrict__ Wg, const float* __restrict__ bg,
    const float* __restrict__ Wb, const float* __restrict__ bb,
    const float* __restrict__ Wk, const float* __restrict__ bk,
    float* __restrict__ cv,      // [B][VDIM], pre-zeroed
    float* __restrict__ aw_out)  // [B][KMAX]
{
    int blk  = blockIdx.x;
    int b    = blk >> 6;          // / NSPLIT
    int s    = blk & (NSPLIT - 1);
    int t    = threadIdx.x;       // 128 threads = 2 waves
    int wave = t >> 6, lane = t & 63;

    __shared__ float dots[24];
    __shared__ float p[24];       // [0..7]=myu [8..15]=1/(2v+eps) [16..23]=w*rsqrt(2pi*v+eps)
    __shared__ float aw_s[KCHUNK];

    // ---- (1) 24 dot products: q[b] . W_{gamma,beta,kappa}[m] ----
    const float4* q4 = (const float4*)(query + (size_t)b * QDIM);
    float4 a0 = q4[lane];
    float4 a1 = q4[lane + 64];
    for (int j = wave; j < 24; j += 2) {
        int set = j >> 3, m = j & 7;
        const float* Wrow = (set == 0 ? Wg : (set == 1 ? Wb : Wk)) + (size_t)m * QDIM;
        const float4* W4 = (const float4*)Wrow;
        float4 w0 = W4[lane], w1 = W4[lane + 64];
        float ss = a0.x * w0.x + a0.y * w0.y + a0.z * w0.z + a0.w * w0.w
                 + a1.x * w1.x + a1.y * w1.y + a1.z * w1.z + a1.w * w1.w;
        #pragma unroll
        for (int off = 32; off; off >>= 1) ss += __shfl_down(ss, off, 64);
        if (lane == 0) dots[j] = ss;
    }
    __syncthreads();

    // ---- (2) mixture params (thread 0) ----
    if (t == 0) {
        float g[8], mx = -1e30f;
        #pragma unroll
        for (int m = 0; m < 8; m++) { g[m] = dots[m] + bg[m]; mx = fmaxf(mx, g[m]); }
        float sum = 0.f;
        #pragma unroll
        for (int m = 0; m < 8; m++) { g[m] = expf(g[m] - mx); sum += g[m]; }
        float inv_sum = 1.f / sum;
        #pragma unroll
        for (int m = 0; m < 8; m++) {
            float w   = g[m] * inv_sum;
            float v   = expf(dots[8 + m]  + bb[m]);
            float myu = expf(dots[16 + m] + bk[m]);
            p[m]      = myu;
            p[8 + m]  = 1.f / (2.f * v + EPSV);
            p[16 + m] = w * rsqrtf(TWO_PI * v + EPSV);
        }
    }
    __syncthreads();

    // ---- (3) aw for this block's k-chunk ----
    int k0 = s * KCHUNK;
    if (t < KCHUNK) {
        int k = k0 + t;
        float j = (float)k;
        float aw = 0.f;
        #pragma unroll
        for (int m = 0; m < 8; m++) {
            float d = j - p[m];
            aw += p[16 + m] * expf(-d * d * p[8 + m]);
        }
        if (mask[(size_t)b * KMAX + k] == 0) aw = NEGINF;
        aw_s[t] = aw;
        aw_out[(size_t)b * KMAX + k] = aw;
    }
    __syncthreads();

    // ---- (4) stream value chunk, accumulate cv ----
    const float4* vb = (const float4*)(value + ((size_t)b * KMAX + k0) * VDIM);
    float4 acc = make_float4(0.f, 0.f, 0.f, 0.f);
    #pragma unroll 8
    for (int kk = 0; kk < KCHUNK; kk++) {
        float a = aw_s[kk];
        float4 v = vb[(size_t)kk * (VDIM / 4) + t];
        acc.x += a * v.x; acc.y += a * v.y; acc.z += a * v.z; acc.w += a * v.w;
    }
    float* cvp = cv + (size_t)b * VDIM + t * 4;
    atomicAdd(cvp + 0, acc.x);
    atomicAdd(cvp + 1, acc.y);
    atomicAdd(cvp + 2, acc.z);
    atomicAdd(cvp + 3, acc.w);
}

extern "C" void kernel_launch(void* const* d_in, const int* in_sizes, int n_in,
                              void* d_out, int out_size, void* d_ws, size_t ws_size,
                              hipStream_t stream) {
    // inputs: 0 key_feat (UNUSED), 1 value, 2 query, 3 mask,
    //         4 W_gamma, 5 b_gamma, 6 W_beta, 7 b_beta, 8 W_kappa, 9 b_kappa
    const float* value = (const float*)d_in[1];
    const float* query = (const float*)d_in[2];
    const int*   mask  = (const int*)d_in[3];
    const float* Wg = (const float*)d_in[4];
    const float* bg = (const float*)d_in[5];
    const float* Wb = (const float*)d_in[6];
    const float* bb = (const float*)d_in[7];
    const float* Wk = (const float*)d_in[8];
    const float* bk = (const float*)d_in[9];

    float* out = (float*)d_out;
    float* cv  = out;                 // [B][VDIM]  = 16384 floats
    float* aw  = out + BB * VDIM;     // [B][KMAX]  = 65536 floats

    // zero the cv accumulator region (d_out is poisoned 0xAA before each call)
    hipMemsetAsync(cv, 0, (size_t)BB * VDIM * sizeof(float), stream);

    gmm_fused_kernel<<<BB * NSPLIT, 128, 0, stream>>>(
        value, query, mask, Wg, bg, Wb, bb, Wk, bk, cv, aw);
}

// Round 3
// 243.586 us; speedup vs baseline: 1.1629x; 1.1093x over previous
//
#include <hip/hip_runtime.h>
#include <math.h>

#define BB     32
#define KMAX   2048
#define QDIM   512
#define VDIM   512
#define NMIX   8
#define EPSV   1e-6f
#define NEGINF -3.40282347e38f
#define TWO_PI 6.28318530717958647692f
#define NSPLIT 64
#define KCHUNK (KMAX / NSPLIT)   // 32
#define AW_SKIP_EPS 1e-12f

// One fused kernel. Grid = BB*NSPLIT blocks x 128 threads.
// Each block: (1) redundantly computes the 24 q-projections for its batch b
// (48 KB of W, L2-resident), (2) derives the 8 Gaussian params, (3) computes
// aw for its 32-k chunk and writes it, (4) EARLY-EXIT: the Gaussian mixture
// underflows to exact fp32 zero for j >~ myu + sqrt(60 v) (~80 for this data),
// so chunks with max|aw| < 1e-12 skip the value stream entirely (error bound
// 1e-12 * 2048 * |value| ~ 2e-9 << 4.2e-2 threshold; NEG_INF masked chunks
// have |aw|=3.4e38 and are never skipped). Active chunks stream value with
// float4 loads and atomically accumulate cv.
__global__ __launch_bounds__(128) void gmm_fused_kernel(
    const float* __restrict__ value,
    const float* __restrict__ query,
    const int*   __restrict__ mask,
    const float* __restrict__ Wg, const float* __restrict__ bg,
    const float* __restrict__ Wb, const float* __restrict__ bb,
    const float* __restrict__ Wk, const float* __restrict__ bk,
    float* __restrict__ cv,      // [B][VDIM], pre-zeroed
    float* __restrict__ aw_out)  // [B][KMAX]
{
    int blk  = blockIdx.x;
    int b    = blk >> 6;          // / NSPLIT
    int s    = blk & (NSPLIT - 1);
    int t    = threadIdx.x;       // 128 threads = 2 waves
    int wave = t >> 6, lane = t & 63;

    __shared__ float dots[24];
    __shared__ float p[24];       // [0..7]=myu [8..15]=1/(2v+eps) [16..23]=w*rsqrt(2pi*v+eps)
    __shared__ float aw_s[KCHUNK];

    // ---- (1) 24 dot products: q[b] . W_{gamma,beta,kappa}[m] ----
    const float4* q4 = (const float4*)(query + (size_t)b * QDIM);
    float4 a0 = q4[lane];
    float4 a1 = q4[lane + 64];
    for (int j = wave; j < 24; j += 2) {
        int set = j >> 3, m = j & 7;
        const float* Wrow = (set == 0 ? Wg : (set == 1 ? Wb : Wk)) + (size_t)m * QDIM;
        const float4* W4 = (const float4*)Wrow;
        float4 w0 = W4[lane], w1 = W4[lane + 64];
        float ss = a0.x * w0.x + a0.y * w0.y + a0.z * w0.z + a0.w * w0.w
                 + a1.x * w1.x + a1.y * w1.y + a1.z * w1.z + a1.w * w1.w;
        #pragma unroll
        for (int off = 32; off; off >>= 1) ss += __shfl_down(ss, off, 64);
        if (lane == 0) dots[j] = ss;
    }
    __syncthreads();

    // ---- (2) mixture params (thread 0) ----
    if (t == 0) {
        float g[8], mx = -1e30f;
        #pragma unroll
        for (int m = 0; m < 8; m++) { g[m] = dots[m] + bg[m]; mx = fmaxf(mx, g[m]); }
        float sum = 0.f;
        #pragma unroll
        for (int m = 0; m < 8; m++) { g[m] = expf(g[m] - mx); sum += g[m]; }
        float inv_sum = 1.f / sum;
        #pragma unroll
        for (int m = 0; m < 8; m++) {
            float w   = g[m] * inv_sum;
            float v   = expf(dots[8 + m]  + bb[m]);
            float myu = expf(dots[16 + m] + bk[m]);
            p[m]      = myu;
            p[8 + m]  = 1.f / (2.f * v + EPSV);
            p[16 + m] = w * rsqrtf(TWO_PI * v + EPSV);
        }
    }
    __syncthreads();

    // ---- (3) aw for this block's k-chunk ----
    int k0 = s * KCHUNK;
    if (t < KCHUNK) {
        int k = k0 + t;
        float j = (float)k;
        float aw = 0.f;
        #pragma unroll
        for (int m = 0; m < 8; m++) {
            float d = j - p[m];
            aw += p[16 + m] * expf(-d * d * p[8 + m]);
        }
        if (mask[(size_t)b * KMAX + k] == 0) aw = NEGINF;
        aw_s[t] = aw;
        aw_out[(size_t)b * KMAX + k] = aw;
    }
    __syncthreads();

    // ---- (4) early exit if this chunk contributes nothing to cv ----
    float mx = 0.f;
    #pragma unroll
    for (int kk = 0; kk < KCHUNK; kk++) mx = fmaxf(mx, fabsf(aw_s[kk]));
    if (mx < AW_SKIP_EPS) return;   // uniform across block

    // ---- (5) stream value chunk, accumulate cv ----
    const float4* vb = (const float4*)(value + ((size_t)b * KMAX + k0) * VDIM);
    float4 acc = make_float4(0.f, 0.f, 0.f, 0.f);
    #pragma unroll 8
    for (int kk = 0; kk < KCHUNK; kk++) {
        float a = aw_s[kk];
        float4 v = vb[(size_t)kk * (VDIM / 4) + t];
        acc.x += a * v.x; acc.y += a * v.y; acc.z += a * v.z; acc.w += a * v.w;
    }
    float* cvp = cv + (size_t)b * VDIM + t * 4;
    atomicAdd(cvp + 0, acc.x);
    atomicAdd(cvp + 1, acc.y);
    atomicAdd(cvp + 2, acc.z);
    atomicAdd(cvp + 3, acc.w);
}

extern "C" void kernel_launch(void* const* d_in, const int* in_sizes, int n_in,
                              void* d_out, int out_size, void* d_ws, size_t ws_size,
                              hipStream_t stream) {
    // inputs: 0 key_feat (UNUSED), 1 value, 2 query, 3 mask,
    //         4 W_gamma, 5 b_gamma, 6 W_beta, 7 b_beta, 8 W_kappa, 9 b_kappa
    const float* value = (const float*)d_in[1];
    const float* query = (const float*)d_in[2];
    const int*   mask  = (const int*)d_in[3];
    const float* Wg = (const float*)d_in[4];
    const float* bg = (const float*)d_in[5];
    const float* Wb = (const float*)d_in[6];
    const float* bb = (const float*)d_in[7];
    const float* Wk = (const float*)d_in[8];
    const float* bk = (const float*)d_in[9];

    float* out = (float*)d_out;
    float* cv  = out;                 // [B][VDIM]  = 16384 floats
    float* aw  = out + BB * VDIM;     // [B][KMAX]  = 65536 floats

    // zero the cv accumulator region (d_out is poisoned 0xAA before each call)
    hipMemsetAsync(cv, 0, (size_t)BB * VDIM * sizeof(float), stream);

    gmm_fused_kernel<<<BB * NSPLIT, 128, 0, stream>>>(
        value, query, mask, Wg, bg, Wb, bb, Wk, bk, cv, aw);
}

// Round 4
// 241.862 us; speedup vs baseline: 1.1712x; 1.0071x over previous
//
#include <hip/hip_runtime.h>
#include <math.h>

#define BB     32
#define KMAX   2048
#define QDIM   512
#define VDIM   512
#define NMIX   8
#define EPSV   1e-6f
#define NEGINF -3.40282347e38f
#define TWO_PI 6.28318530717958647692f
#define NSPLIT 64
#define KCHUNK (KMAX / NSPLIT)   // 32
#define ASPLIT 4                 // kernel-A blocks per batch
#define KQ     (KMAX / ASPLIT)   // 512 k's per A-block
#define AW_SKIP_EPS 1e-12f

// Kernel A: grid = BB*ASPLIT (128) blocks x 256 threads.
// Per block: compute the 24 q-projections for batch b (once per block, not per
// k-chunk), derive the 8 Gaussian params, write aw (mask applied) for its
// 512-k quarter with coalesced stores, and zero its 128-float slice of cv.
__global__ __launch_bounds__(256) void gmm_aw_kernel(
    const float* __restrict__ query,
    const int*   __restrict__ mask,
    const float* __restrict__ Wg, const float* __restrict__ bg,
    const float* __restrict__ Wb, const float* __restrict__ bb,
    const float* __restrict__ Wk, const float* __restrict__ bk,
    float* __restrict__ cv,      // [B][VDIM] (zeroed here, accumulated in B)
    float* __restrict__ aw_out)  // [B][KMAX]
{
    int blk  = blockIdx.x;
    int b    = blk >> 2;          // / ASPLIT
    int sub  = blk & (ASPLIT - 1);
    int t    = threadIdx.x;       // 256 threads = 4 waves
    int wave = t >> 6, lane = t & 63;

    __shared__ float dots[24];
    __shared__ float p[24];       // [0..7]=myu [8..15]=1/(2v+eps) [16..23]=w*rsqrt(2pi*v+eps)

    // ---- 24 dot products: q[b] . W_{gamma,beta,kappa}[m] (6 per wave) ----
    const float4* q4 = (const float4*)(query + (size_t)b * QDIM);
    float4 a0 = q4[lane];
    float4 a1 = q4[lane + 64];
    for (int j = wave; j < 24; j += 4) {
        int set = j >> 3, m = j & 7;
        const float* Wrow = (set == 0 ? Wg : (set == 1 ? Wb : Wk)) + (size_t)m * QDIM;
        const float4* W4 = (const float4*)Wrow;
        float4 w0 = W4[lane], w1 = W4[lane + 64];
        float ss = a0.x * w0.x + a0.y * w0.y + a0.z * w0.z + a0.w * w0.w
                 + a1.x * w1.x + a1.y * w1.y + a1.z * w1.z + a1.w * w1.w;
        #pragma unroll
        for (int off = 32; off; off >>= 1) ss += __shfl_down(ss, off, 64);
        if (lane == 0) dots[j] = ss;
    }
    __syncthreads();

    if (t == 0) {
        float g[8], mx = -1e30f;
        #pragma unroll
        for (int m = 0; m < 8; m++) { g[m] = dots[m] + bg[m]; mx = fmaxf(mx, g[m]); }
        float sum = 0.f;
        #pragma unroll
        for (int m = 0; m < 8; m++) { g[m] = expf(g[m] - mx); sum += g[m]; }
        float inv_sum = 1.f / sum;
        #pragma unroll
        for (int m = 0; m < 8; m++) {
            float w   = g[m] * inv_sum;
            float v   = expf(dots[8 + m]  + bb[m]);
            float myu = expf(dots[16 + m] + bk[m]);
            p[m]      = myu;
            p[8 + m]  = 1.f / (2.f * v + EPSV);
            p[16 + m] = w * rsqrtf(TWO_PI * v + EPSV);
        }
    }
    __syncthreads();

    // ---- aw for this block's 512-k quarter (coalesced) ----
    #pragma unroll
    for (int i = 0; i < KQ / 256; i++) {
        int k = sub * KQ + t + 256 * i;
        float j = (float)k;
        float aw = 0.f;
        #pragma unroll
        for (int m = 0; m < 8; m++) {
            float d = j - p[m];
            aw += p[16 + m] * expf(-d * d * p[8 + m]);
        }
        if (mask[(size_t)b * KMAX + k] == 0) aw = NEGINF;
        aw_out[(size_t)b * KMAX + k] = aw;
    }

    // ---- zero this block's cv slice (128 floats = 32 float4) ----
    if (t < 32) {
        ((float4*)(cv + (size_t)b * VDIM + sub * 128))[t] =
            make_float4(0.f, 0.f, 0.f, 0.f);
    }
}

// Kernel B: grid = BB*NSPLIT (2048) blocks x 128 threads.
// Loads its chunk's 32 precomputed aw values; if max|aw| < 1e-12 the Gaussian
// mixture has underflowed to fp32 zero for the whole chunk (error bound
// 1e-12 * 2048 * |value| ~ 2e-9 << threshold; NEG_INF masked chunks have
// |aw|=3.4e38, never skipped) -> skip the value stream. Active chunks stream
// value with float4 loads and atomically accumulate into cv.
__global__ __launch_bounds__(128) void gmm_cv_kernel(
    const float* __restrict__ value,
    const float* __restrict__ aw_out,
    float* __restrict__ cv)
{
    int blk = blockIdx.x;
    int b   = blk >> 6;           // / NSPLIT
    int s   = blk & (NSPLIT - 1);
    int t   = threadIdx.x;        // 128 threads
    __shared__ float aw_s[KCHUNK];

    int k0 = s * KCHUNK;
    if (t < KCHUNK) aw_s[t] = aw_out[(size_t)b * KMAX + k0 + t];
    __syncthreads();

    float mx = 0.f;
    #pragma unroll
    for (int kk = 0; kk < KCHUNK; kk++) mx = fmaxf(mx, fabsf(aw_s[kk]));
    if (mx < AW_SKIP_EPS) return;   // uniform across block

    const float4* vb = (const float4*)(value + ((size_t)b * KMAX + k0) * VDIM);
    float4 acc = make_float4(0.f, 0.f, 0.f, 0.f);
    #pragma unroll 8
    for (int kk = 0; kk < KCHUNK; kk++) {
        float a = aw_s[kk];
        float4 v = vb[(size_t)kk * (VDIM / 4) + t];
        acc.x += a * v.x; acc.y += a * v.y; acc.z += a * v.z; acc.w += a * v.w;
    }
    float* cvp = cv + (size_t)b * VDIM + t * 4;
    atomicAdd(cvp + 0, acc.x);
    atomicAdd(cvp + 1, acc.y);
    atomicAdd(cvp + 2, acc.z);
    atomicAdd(cvp + 3, acc.w);
}

extern "C" void kernel_launch(void* const* d_in, const int* in_sizes, int n_in,
                              void* d_out, int out_size, void* d_ws, size_t ws_size,
                              hipStream_t stream) {
    // inputs: 0 key_feat (UNUSED), 1 value, 2 query, 3 mask,
    //         4 W_gamma, 5 b_gamma, 6 W_beta, 7 b_beta, 8 W_kappa, 9 b_kappa
    const float* value = (const float*)d_in[1];
    const float* query = (const float*)d_in[2];
    const int*   mask  = (const int*)d_in[3];
    const float* Wg = (const float*)d_in[4];
    const float* bg = (const float*)d_in[5];
    const float* Wb = (const float*)d_in[6];
    const float* bb = (const float*)d_in[7];
    const float* Wk = (const float*)d_in[8];
    const float* bk = (const float*)d_in[9];

    float* out = (float*)d_out;
    float* cv  = out;                 // [B][VDIM]  = 16384 floats
    float* aw  = out + BB * VDIM;     // [B][KMAX]  = 65536 floats

    gmm_aw_kernel<<<BB * ASPLIT, 256, 0, stream>>>(
        query, mask, Wg, bg, Wb, bb, Wk, bk, cv, aw);
    gmm_cv_kernel<<<BB * NSPLIT, 128, 0, stream>>>(value, aw, cv);
}